// Round 5
// baseline (448.721 us; speedup 1.0000x reference)
//
#include <hip/hip_runtime.h>
#include <cstdint>
#include <cstddef>

typedef float  v4f __attribute__((ext_vector_type(4)));
typedef short  v8s __attribute__((ext_vector_type(8)));
typedef int    v4i __attribute__((ext_vector_type(4)));
typedef unsigned long long u64;

#define BB 8
#define NN 2048
#define DD 128
#define TI 16
#define NEGV (-9e15f)

__device__ __forceinline__ unsigned short f2bf(float x) {
  unsigned u = __float_as_uint(x);
  u = u + 0x7FFFu + ((u >> 16) & 1u);   // round-to-nearest-even
  return (unsigned short)(u >> 16);
}

// packed f32x2 -> bf16x2, RTNE (same rounding as f2bf)
__device__ __forceinline__ unsigned cvt_pk_bf16(float lo, float hi) {
  unsigned r;
  asm("v_cvt_pk_bf16_f32 %0, %1, %2" : "=v"(r) : "v"(lo), "v"(hi));
  return r;
}

// ---------------------------------------------------------------------------
// K1 (MFMA): Wh = h @ W, Wh1 = Wh·a[:128], Wh2 = Wh·a[128:], whbT = bf16(Wh)^T.
// Unchanged (correctness-verified).
// ---------------------------------------------------------------------------
__global__ __launch_bounds__(256) void gat_k1(
    const float* __restrict__ h, const float* __restrict__ W, const float* __restrict__ a,
    short* __restrict__ whbT, float* __restrict__ wh1g, float* __restrict__ wh2g)
{
  __shared__ __align__(16) unsigned short wT[DD * 136];
  __shared__ __align__(16) unsigned short staging[DD * 72];

  const int tid  = threadIdx.x;
  const int lane = tid & 63;
  const int wid  = tid >> 6;
  const int m16  = lane & 15;
  const int quad = lane >> 4;
  const int b    = blockIdx.y;
  const int i0   = blockIdx.x * 64;

  {
    const v4f* W4 = (const v4f*)W;
    #pragma unroll
    for (int it = 0; it < 16; it++) {
      int idx = it * 256 + tid;
      int k  = idx >> 5;
      int c4 = (idx & 31) * 4;
      v4f wv = W4[idx];
      #pragma unroll
      for (int q = 0; q < 4; q++)
        wT[(c4 + q) * 136 + k] = f2bf(wv[q]);
    }
  }

  const float* hrow = h + (size_t)(b * NN + i0 + wid * 16 + m16) * DD;
  v8s af[4];
  #pragma unroll
  for (int ks = 0; ks < 4; ks++) {
    v4f x0 = *(const v4f*)(hrow + ks * 32 + quad * 8);
    v4f x1 = *(const v4f*)(hrow + ks * 32 + quad * 8 + 4);
    v8s t;
    t[0] = (short)f2bf(x0.x); t[1] = (short)f2bf(x0.y);
    t[2] = (short)f2bf(x0.z); t[3] = (short)f2bf(x0.w);
    t[4] = (short)f2bf(x1.x); t[5] = (short)f2bf(x1.y);
    t[6] = (short)f2bf(x1.z); t[7] = (short)f2bf(x1.w);
    af[ks] = t;
  }
  __syncthreads();

  v4f acc[8];
  #pragma unroll
  for (int t = 0; t < 8; t++) acc[t] = (v4f){0.f, 0.f, 0.f, 0.f};

  #pragma unroll
  for (int ks = 0; ks < 4; ks++) {
    #pragma unroll
    for (int t = 0; t < 8; t++) {
      v8s bf = *(const v8s*)&wT[(t * 16 + m16) * 136 + ks * 32 + quad * 8];
      acc[t] = __builtin_amdgcn_mfma_f32_16x16x32_bf16(af[ks], bf, acc[t], 0, 0, 0);
    }
  }

  {
    float a1v[8], a2v[8];
    #pragma unroll
    for (int t = 0; t < 8; t++) {
      a1v[t] = a[t * 16 + m16];
      a2v[t] = a[DD + t * 16 + m16];
    }
    #pragma unroll
    for (int r = 0; r < 4; r++) {
      float p1 = 0.f, p2 = 0.f;
      #pragma unroll
      for (int t = 0; t < 8; t++) {
        p1 += acc[t][r] * a1v[t];
        p2 += acc[t][r] * a2v[t];
      }
      #pragma unroll
      for (int off = 8; off > 0; off >>= 1) {
        p1 += __shfl_xor(p1, off);
        p2 += __shfl_xor(p2, off);
      }
      if (m16 == 0) {
        int gi = b * NN + i0 + wid * 16 + quad * 4 + r;
        wh1g[gi] = p1;
        wh2g[gi] = p2;
      }
    }
  }

  #pragma unroll
  for (int t = 0; t < 8; t++)
    #pragma unroll
    for (int r = 0; r < 4; r++)
      staging[(t * 16 + m16) * 72 + wid * 16 + quad * 4 + r] = f2bf(acc[t][r]);
  __syncthreads();

  #pragma unroll
  for (int it = 0; it < 4; it++) {
    int idx = it * 256 + tid;
    int c  = idx >> 3;
    int i8 = idx & 7;
    v8s val = *(const v8s*)&staging[c * 72 + i8 * 8];
    *(v8s*)(whbT + (size_t)b * DD * NN + (size_t)c * NN + i0 + i8 * 8) = val;
  }
}

// ---------------------------------------------------------------------------
// K0: streaming adj pass (unchanged; measured ~22us, at adj-read roofline).
// ---------------------------------------------------------------------------
__global__ __launch_bounds__(256) void gat_k0(
    const int* __restrict__ adj, const float* __restrict__ wh1g,
    const float* __restrict__ wh2g, unsigned* __restrict__ maskg,
    float* __restrict__ msg, float* __restrict__ rsg)
{
  const int tid  = threadIdx.x;
  const int lane = tid & 63;
  const int wid  = tid >> 6;
  const int b    = blockIdx.y;
  const int i    = blockIdx.x * 4 + wid;
  const size_t row = (size_t)b * NN + i;

  const v4i* arow = (const v4i*)(adj + row * NN);
  const v4f* w2   = (const v4f*)(wh2g + (size_t)b * NN);
  const float wh1v = wh1g[row];

  float e[32];
  float m = -INFINITY;
  unsigned mbits = 0u;
  #pragma unroll
  for (int u = 0; u < 8; u++) {
    v4i av  = __builtin_nontemporal_load(&arow[u * 64 + lane]);
    v4f w2v = w2[u * 64 + lane];
    #pragma unroll
    for (int q = 0; q < 4; q++) {
      bool mk = av[q] > 0;
      float x = wh1v + w2v[q];
      float ev = mk ? (x > 0.f ? x : 0.2f * x) : NEGV;
      e[u * 4 + q] = ev;
      m = fmaxf(m, ev);
      mbits |= (mk ? 1u : 0u) << (u * 4 + q);
    }
  }
  maskg[row * 64 + lane] = mbits;

  #pragma unroll
  for (int off = 32; off > 0; off >>= 1) m = fmaxf(m, __shfl_xor(m, off));
  float s = 0.f;
  #pragma unroll
  for (int k = 0; k < 32; k++) s += __expf(e[k] - m);
  #pragma unroll
  for (int off = 32; off > 0; off >>= 1) s += __shfl_xor(s, off);

  if (lane == 0) { msg[row] = m; rsg[row] = 1.f / s; }
}

// ---------------------------------------------------------------------------
// K2 v5: 8 waves/block (512 thr), each wave owns a 256-wide j-quarter.
// Same per-wave structure as v4 (store-layout att, wave-private LDS relayout,
// loads-before-stores). 32 waves/CU (2x v4) to fix the MLP starvation.
// ---------------------------------------------------------------------------
__global__ __launch_bounds__(512, 8) void gat_k2(
    const float* __restrict__ h, const unsigned* __restrict__ maskg,
    const short* __restrict__ whbT, const float* __restrict__ wh1g,
    const float* __restrict__ wh2g, const float* __restrict__ msg,
    const float* __restrict__ rsg, float* __restrict__ out,
    float* __restrict__ attout)
{
  // 32 KB: [0,8K) wh2s, [8K, 8K+17.4K) 8 per-wave atiles; whole 32 KB = red in epilogue
  __shared__ __align__(16) float smem[8192];
  __shared__ unsigned masks[TI * 68];
  __shared__ float wh1s[TI], ms_s[TI], rs_s[TI];

  const int tid  = threadIdx.x;
  const int lane = tid & 63;
  const int wid  = tid >> 6;        // 0..7
  const int m16  = lane & 15;
  const int quad = lane >> 4;
  const int bid  = blockIdx.x;
  const int b    = bid & 7;         // XCD swizzle: one batch per XCD
  const int i0   = (bid >> 3) * TI;

  float* wh2s = smem;
  unsigned short* atile = (unsigned short*)(smem + 2048) + wid * (TI * 68);

  {
    const v4f* w2g4 = (const v4f*)(wh2g + (size_t)b * NN);
    ((v4f*)wh2s)[tid] = w2g4[tid];          // 512 v4f with 512 threads
  }
  {
    const unsigned* mg = maskg + (size_t)(b * NN + i0) * 64;
    #pragma unroll
    for (int it = 0; it < 2; it++) {
      int idx = it * 512 + tid;
      masks[(idx >> 6) * 68 + (idx & 63)] = mg[idx];
    }
  }
  if (tid < TI) {
    wh1s[tid] = wh1g[b * NN + i0 + tid];
    ms_s[tid] = msg[b * NN + i0 + tid];
    rs_s[tid] = rsg[b * NN + i0 + tid];
  }
  __syncthreads();

  // per-lane row scalars for the 4 rows this lane computes (rows it*4+quad)
  float wh1r[4], mir[4], rsr[4];
  #pragma unroll
  for (int it = 0; it < 4; it++) {
    wh1r[it] = wh1s[it * 4 + quad];
    mir[it]  = ms_s[it * 4 + quad];
    rsr[it]  = rs_s[it * 4 + quad];
  }

  const short* whbT_b = whbT + (size_t)b * DD * NN;
  float* attbase = attout + (size_t)(b * NN + i0) * NN;

  v4f acc[8];
  #pragma unroll
  for (int t = 0; t < 8; t++) acc[t] = (v4f){0.f, 0.f, 0.f, 0.f};

  for (int c = 0; c < 4; c++) {
    const int j0 = wid * 256 + c * 64;
    const int jb = j0 + quad * 8;

    // 1) B-fragment loads FIRST (older than this chunk's stores)
    v8s bfr0[8], bfr1[8];
    #pragma unroll
    for (int t = 0; t < 8; t++)
      bfr0[t] = *(const v8s*)(whbT_b + (size_t)(t * 16 + m16) * NN + jb);
    #pragma unroll
    for (int t = 0; t < 8; t++)
      bfr1[t] = *(const v8s*)(whbT_b + (size_t)(t * 16 + m16) * NN + jb + 32);

    // 2) attention in STORE layout: lane -> (row = it*4+quad, cols m16*4..+3)
    const int ubit = (j0 >> 8) << 2;
    const int wq   = ((j0 >> 2) & 63) + m16;
    v4f w2v = ((const v4f*)wh2s)[(j0 >> 2) + m16];
    #pragma unroll
    for (int it = 0; it < 4; it++) {
      const int row = it * 4 + quad;
      unsigned mw = masks[row * 68 + wq];
      v4f at;
      #pragma unroll
      for (int q = 0; q < 4; q++) {
        float x = wh1r[it] + w2v[q];
        float ev = ((mw >> (ubit + q)) & 1u) ? (x > 0.f ? x : 0.2f * x) : NEGV;
        at[q] = __expf(ev - mir[it]) * rsr[it];
      }
      *(v4f*)(attbase + (size_t)row * NN + j0 + m16 * 4) = at;   // plain store
      unsigned lo = cvt_pk_bf16(at[0], at[1]);
      unsigned hi = cvt_pk_bf16(at[2], at[3]);
      u64 dv = (u64)lo | ((u64)hi << 32);
      *(u64*)&atile[row * 68 + m16 * 4] = dv;
    }

    // 3) A-fragments back from LDS in MFMA layout (row = m16, k = ks*32+quad*8)
    union { v8s s; u64 d[2]; } af0, af1;
    af0.d[0] = *(const u64*)&atile[m16 * 68 + quad * 8];
    af0.d[1] = *(const u64*)&atile[m16 * 68 + quad * 8 + 4];
    af1.d[0] = *(const u64*)&atile[m16 * 68 + 32 + quad * 8];
    af1.d[1] = *(const u64*)&atile[m16 * 68 + 32 + quad * 8 + 4];

    // 4) MFMA: 8 d-tiles x K=64
    #pragma unroll
    for (int t = 0; t < 8; t++)
      acc[t] = __builtin_amdgcn_mfma_f32_16x16x32_bf16(af0.s, bfr0[t], acc[t], 0, 0, 0);
    #pragma unroll
    for (int t = 0; t < 8; t++)
      acc[t] = __builtin_amdgcn_mfma_f32_16x16x32_bf16(af1.s, bfr1[t], acc[t], 0, 0, 0);
  }

  // ---- cross-wave reduction of h' partials: 8 waves -> 4 LDS slots -> sum
  __syncthreads();                  // wh2s/atile dead; reuse smem as red[4][16][128]
  float* red = smem;
  if (wid < 4) {
    #pragma unroll
    for (int t = 0; t < 8; t++)
      #pragma unroll
      for (int r = 0; r < 4; r++)
        red[wid * (TI * DD) + (quad * 4 + r) * DD + t * 16 + m16] = acc[t][r];
  }
  __syncthreads();
  if (wid >= 4) {
    float* slot = red + (wid - 4) * (TI * DD);
    #pragma unroll
    for (int t = 0; t < 8; t++)
      #pragma unroll
      for (int r = 0; r < 4; r++) {
        int o = (quad * 4 + r) * DD + t * 16 + m16;
        slot[o] += acc[t][r];
      }
  }
  __syncthreads();

  {
    const size_t base = (size_t)(b * NN + i0) * DD;
    v4f s0 = ((const v4f*)red)[tid];
    v4f s1 = ((const v4f*)red)[tid + 512];
    v4f s2 = ((const v4f*)red)[tid + 1024];
    v4f s3 = ((const v4f*)red)[tid + 1536];
    v4f hv = *(const v4f*)(h + base + (size_t)tid * 4);
    v4f o  = hv + s0 + s1 + s2 + s3;
    *(v4f*)(out + base + (size_t)tid * 4) = o;
  }
}

extern "C" void kernel_launch(void* const* d_in, const int* in_sizes, int n_in,
                              void* d_out, int out_size, void* d_ws, size_t ws_size,
                              hipStream_t stream) {
  const float* h  = (const float*)d_in[0];
  const int* adj  = (const int*)d_in[1];
  const float* W  = (const float*)d_in[2];
  const float* a  = (const float*)d_in[3];

  float* out    = (float*)d_out;
  float* attout = out + (size_t)BB * NN * DD;

  char* ws = (char*)d_ws;
  short* whbT = (short*)ws;                      ws += (size_t)BB * DD * NN * 2;  // 8.39MB
  float* wh1  = (float*)ws;                      ws += (size_t)BB * NN * 4;
  float* wh2  = (float*)ws;                      ws += (size_t)BB * NN * 4;
  float* msg  = (float*)ws;                      ws += (size_t)BB * NN * 4;
  float* rsg  = (float*)ws;                      ws += (size_t)BB * NN * 4;
  unsigned* maskg = (unsigned*)ws;               // 4MB

  gat_k1<<<dim3(NN / 64, BB), 256, 0, stream>>>(h, W, a, whbT, wh1, wh2);
  gat_k0<<<dim3(NN / 4, BB), 256, 0, stream>>>(adj, wh1, wh2, maskg, msg, rsg);
  gat_k2<<<dim3(NN / TI * BB), 512, 0, stream>>>(h, maskg, whbT, wh1, wh2, msg, rsg, out, attout);
}

// Round 6
// 361.179 us; speedup vs baseline: 1.2424x; 1.2424x over previous
//
#include <hip/hip_runtime.h>
#include <cstdint>
#include <cstddef>

typedef float  v4f __attribute__((ext_vector_type(4)));
typedef short  v8s __attribute__((ext_vector_type(8)));
typedef int    v4i __attribute__((ext_vector_type(4)));
typedef unsigned long long u64;

#define BB 8
#define NN 2048
#define DD 128
#define TR 8          // K2 row tile (halved from 16 to double block count)
#define NEGV (-9e15f)

__device__ __forceinline__ unsigned short f2bf(float x) {
  unsigned u = __float_as_uint(x);
  u = u + 0x7FFFu + ((u >> 16) & 1u);   // round-to-nearest-even
  return (unsigned short)(u >> 16);
}

// packed f32x2 -> bf16x2, RTNE (same rounding as f2bf)
__device__ __forceinline__ unsigned cvt_pk_bf16(float lo, float hi) {
  unsigned r;
  asm("v_cvt_pk_bf16_f32 %0, %1, %2" : "=v"(r) : "v"(lo), "v"(hi));
  return r;
}

// ---------------------------------------------------------------------------
// K1 (MFMA): Wh = h @ W, Wh1 = Wh·a[:128], Wh2 = Wh·a[128:], whbT = bf16(Wh)^T.
// Unchanged (correctness-verified).
// ---------------------------------------------------------------------------
__global__ __launch_bounds__(256) void gat_k1(
    const float* __restrict__ h, const float* __restrict__ W, const float* __restrict__ a,
    short* __restrict__ whbT, float* __restrict__ wh1g, float* __restrict__ wh2g)
{
  __shared__ __align__(16) unsigned short wT[DD * 136];
  __shared__ __align__(16) unsigned short staging[DD * 72];

  const int tid  = threadIdx.x;
  const int lane = tid & 63;
  const int wid  = tid >> 6;
  const int m16  = lane & 15;
  const int quad = lane >> 4;
  const int b    = blockIdx.y;
  const int i0   = blockIdx.x * 64;

  {
    const v4f* W4 = (const v4f*)W;
    #pragma unroll
    for (int it = 0; it < 16; it++) {
      int idx = it * 256 + tid;
      int k  = idx >> 5;
      int c4 = (idx & 31) * 4;
      v4f wv = W4[idx];
      #pragma unroll
      for (int q = 0; q < 4; q++)
        wT[(c4 + q) * 136 + k] = f2bf(wv[q]);
    }
  }

  const float* hrow = h + (size_t)(b * NN + i0 + wid * 16 + m16) * DD;
  v8s af[4];
  #pragma unroll
  for (int ks = 0; ks < 4; ks++) {
    v4f x0 = *(const v4f*)(hrow + ks * 32 + quad * 8);
    v4f x1 = *(const v4f*)(hrow + ks * 32 + quad * 8 + 4);
    v8s t;
    t[0] = (short)f2bf(x0.x); t[1] = (short)f2bf(x0.y);
    t[2] = (short)f2bf(x0.z); t[3] = (short)f2bf(x0.w);
    t[4] = (short)f2bf(x1.x); t[5] = (short)f2bf(x1.y);
    t[6] = (short)f2bf(x1.z); t[7] = (short)f2bf(x1.w);
    af[ks] = t;
  }
  __syncthreads();

  v4f acc[8];
  #pragma unroll
  for (int t = 0; t < 8; t++) acc[t] = (v4f){0.f, 0.f, 0.f, 0.f};

  #pragma unroll
  for (int ks = 0; ks < 4; ks++) {
    #pragma unroll
    for (int t = 0; t < 8; t++) {
      v8s bf = *(const v8s*)&wT[(t * 16 + m16) * 136 + ks * 32 + quad * 8];
      acc[t] = __builtin_amdgcn_mfma_f32_16x16x32_bf16(af[ks], bf, acc[t], 0, 0, 0);
    }
  }

  {
    float a1v[8], a2v[8];
    #pragma unroll
    for (int t = 0; t < 8; t++) {
      a1v[t] = a[t * 16 + m16];
      a2v[t] = a[DD + t * 16 + m16];
    }
    #pragma unroll
    for (int r = 0; r < 4; r++) {
      float p1 = 0.f, p2 = 0.f;
      #pragma unroll
      for (int t = 0; t < 8; t++) {
        p1 += acc[t][r] * a1v[t];
        p2 += acc[t][r] * a2v[t];
      }
      #pragma unroll
      for (int off = 8; off > 0; off >>= 1) {
        p1 += __shfl_xor(p1, off);
        p2 += __shfl_xor(p2, off);
      }
      if (m16 == 0) {
        int gi = b * NN + i0 + wid * 16 + quad * 4 + r;
        wh1g[gi] = p1;
        wh2g[gi] = p2;
      }
    }
  }

  #pragma unroll
  for (int t = 0; t < 8; t++)
    #pragma unroll
    for (int r = 0; r < 4; r++)
      staging[(t * 16 + m16) * 72 + wid * 16 + quad * 4 + r] = f2bf(acc[t][r]);
  __syncthreads();

  #pragma unroll
  for (int it = 0; it < 4; it++) {
    int idx = it * 256 + tid;
    int c  = idx >> 3;
    int i8 = idx & 7;
    v8s val = *(const v8s*)&staging[c * 72 + i8 * 8];
    *(v8s*)(whbT + (size_t)b * DD * NN + (size_t)c * NN + i0 + i8 * 8) = val;
  }
}

// ---------------------------------------------------------------------------
// K0: streaming adj pass (unchanged; ~22us, at adj-read roofline).
// ---------------------------------------------------------------------------
__global__ __launch_bounds__(256) void gat_k0(
    const int* __restrict__ adj, const float* __restrict__ wh1g,
    const float* __restrict__ wh2g, unsigned* __restrict__ maskg,
    float* __restrict__ msg, float* __restrict__ rsg)
{
  const int tid  = threadIdx.x;
  const int lane = tid & 63;
  const int wid  = tid >> 6;
  const int b    = blockIdx.y;
  const int i    = blockIdx.x * 4 + wid;
  const size_t row = (size_t)b * NN + i;

  const v4i* arow = (const v4i*)(adj + row * NN);
  const v4f* w2   = (const v4f*)(wh2g + (size_t)b * NN);
  const float wh1v = wh1g[row];

  float e[32];
  float m = -INFINITY;
  unsigned mbits = 0u;
  #pragma unroll
  for (int u = 0; u < 8; u++) {
    v4i av  = __builtin_nontemporal_load(&arow[u * 64 + lane]);
    v4f w2v = w2[u * 64 + lane];
    #pragma unroll
    for (int q = 0; q < 4; q++) {
      bool mk = av[q] > 0;
      float x = wh1v + w2v[q];
      float ev = mk ? (x > 0.f ? x : 0.2f * x) : NEGV;
      e[u * 4 + q] = ev;
      m = fmaxf(m, ev);
      mbits |= (mk ? 1u : 0u) << (u * 4 + q);
    }
  }
  maskg[row * 64 + lane] = mbits;

  #pragma unroll
  for (int off = 32; off > 0; off >>= 1) m = fmaxf(m, __shfl_xor(m, off));
  float s = 0.f;
  #pragma unroll
  for (int k = 0; k < 32; k++) s += __expf(e[k] - m);
  #pragma unroll
  for (int off = 32; off > 0; off >>= 1) s += __shfl_xor(s, off);

  if (lane == 0) { msg[row] = m; rsg[row] = 1.f / s; }
}

// ---------------------------------------------------------------------------
// K2 v6: r4 inner loop, TR=8 rows/block -> 2048 blocks, ~19.7KB LDS ->
// 8 blocks/CU = 32 waves/CU (2x r4). 256 thr, (256,4): proven no-spill config.
// MFMA M-dim half-wasted (atile rows 8-15 zeroed once) - MfmaUtil is 1.4%,
// so free. Epilogue: only quads 0-1 carry nonzero rows.
// ---------------------------------------------------------------------------
__global__ __launch_bounds__(256, 4) void gat_k2(
    const float* __restrict__ h, const unsigned* __restrict__ maskg,
    const short* __restrict__ whbT, const float* __restrict__ wh1g,
    const float* __restrict__ wh2g, const float* __restrict__ msg,
    const float* __restrict__ rsg, float* __restrict__ out,
    float* __restrict__ attout)
{
  // [0,2048) floats: wh2s. [2048,4352) floats: 4 per-wave atiles (16x72 shorts each).
  // Epilogue: first 4096 floats reused as red[4][8][128].
  __shared__ __align__(16) float smem[4352];
  __shared__ unsigned masks[TR * 68];
  __shared__ float wh1s[TR], ms_s[TR], rs_s[TR];

  const int tid  = threadIdx.x;
  const int lane = tid & 63;
  const int wid  = tid >> 6;
  const int m16  = lane & 15;
  const int quad = lane >> 4;
  const int bid  = blockIdx.x;
  const int b    = bid & 7;            // XCD swizzle: one batch per XCD
  const int i0   = (bid >> 3) * TR;

  float* wh2s = smem;
  unsigned short* atile = (unsigned short*)(smem + 2048) + wid * (16 * 72);

  {
    const v4f* w2g4 = (const v4f*)(wh2g + (size_t)b * NN);
    ((v4f*)wh2s)[tid]       = w2g4[tid];
    ((v4f*)wh2s)[tid + 256] = w2g4[tid + 256];
  }
  {
    const unsigned* mg = maskg + (size_t)(b * NN + i0) * 64;
    #pragma unroll
    for (int it = 0; it < 2; it++) {
      int idx = it * 256 + tid;
      masks[(idx >> 6) * 68 + (idx & 63)] = mg[idx];
    }
  }
  // zero atile rows 8..15 once (their MFMA A rows contribute zero forever)
  {
    u64* az = (u64*)(atile + 8 * 72);   // 576 shorts = 144 u64
    for (int idx = lane; idx < 144; idx += 64) az[idx] = 0ull;
  }
  if (tid < TR) {
    wh1s[tid] = wh1g[b * NN + i0 + tid];
    ms_s[tid] = msg[b * NN + i0 + tid];
    rs_s[tid] = rsg[b * NN + i0 + tid];
  }
  __syncthreads();

  // per-lane row scalars for the 2 rows this lane computes (rows it*4+quad)
  float wh1r[2], mir[2], rsr[2];
  #pragma unroll
  for (int it = 0; it < 2; it++) {
    wh1r[it] = wh1s[it * 4 + quad];
    mir[it]  = ms_s[it * 4 + quad];
    rsr[it]  = rs_s[it * 4 + quad];
  }

  const short* whbT_b = whbT + (size_t)b * DD * NN;
  float* attbase = attout + (size_t)(b * NN + i0) * NN;

  v4f acc[8];
  #pragma unroll
  for (int t = 0; t < 8; t++) acc[t] = (v4f){0.f, 0.f, 0.f, 0.f};

  for (int c = 0; c < 8; c++) {
    const int j0 = wid * 512 + c * 64;
    const int jb = j0 + quad * 8;

    // 1) B-fragment loads FIRST (older than this chunk's stores)
    v8s bfr0[8], bfr1[8];
    #pragma unroll
    for (int t = 0; t < 8; t++)
      bfr0[t] = *(const v8s*)(whbT_b + (size_t)(t * 16 + m16) * NN + jb);
    #pragma unroll
    for (int t = 0; t < 8; t++)
      bfr1[t] = *(const v8s*)(whbT_b + (size_t)(t * 16 + m16) * NN + jb + 32);

    // 2) attention in STORE layout: lane -> (row = it*4+quad, cols m16*4..+3)
    const int ubit = (j0 >> 8) << 2;
    const int wq   = ((j0 >> 2) & 63) + m16;
    v4f w2v = ((const v4f*)wh2s)[(j0 >> 2) + m16];
    #pragma unroll
    for (int it = 0; it < 2; it++) {
      const int row = it * 4 + quad;
      unsigned mw = masks[row * 68 + wq];
      v4f at;
      #pragma unroll
      for (int q = 0; q < 4; q++) {
        float x = wh1r[it] + w2v[q];
        float ev = ((mw >> (ubit + q)) & 1u) ? (x > 0.f ? x : 0.2f * x) : NEGV;
        at[q] = __expf(ev - mir[it]) * rsr[it];
      }
      *(v4f*)(attbase + (size_t)row * NN + j0 + m16 * 4) = at;   // plain store, full lines
      unsigned lo = cvt_pk_bf16(at[0], at[1]);
      unsigned hi = cvt_pk_bf16(at[2], at[3]);
      u64 dv = (u64)lo | ((u64)hi << 32);
      *(u64*)&atile[row * 72 + m16 * 4] = dv;
    }

    // 3) A-fragments from LDS in MFMA layout (row = m16, k = ks*32+quad*8)
    union { v8s s; u64 d[2]; } af0, af1;
    af0.d[0] = *(const u64*)&atile[m16 * 72 + quad * 8];
    af0.d[1] = *(const u64*)&atile[m16 * 72 + quad * 8 + 4];
    af1.d[0] = *(const u64*)&atile[m16 * 72 + 32 + quad * 8];
    af1.d[1] = *(const u64*)&atile[m16 * 72 + 32 + quad * 8 + 4];

    // 4) MFMA: 8 d-tiles x K=64
    #pragma unroll
    for (int t = 0; t < 8; t++)
      acc[t] = __builtin_amdgcn_mfma_f32_16x16x32_bf16(af0.s, bfr0[t], acc[t], 0, 0, 0);
    #pragma unroll
    for (int t = 0; t < 8; t++)
      acc[t] = __builtin_amdgcn_mfma_f32_16x16x32_bf16(af1.s, bfr1[t], acc[t], 0, 0, 0);
  }

  // ---- cross-wave reduction: rows 0..7 live in quads 0,1 only
  __syncthreads();                  // main-loop LDS dead; reuse as red[4][8][128]
  float* red = smem;
  if (quad < 2) {
    #pragma unroll
    for (int t = 0; t < 8; t++)
      #pragma unroll
      for (int r = 0; r < 4; r++)
        red[wid * (TR * DD) + (quad * 4 + r) * DD + t * 16 + m16] = acc[t][r];
  }
  __syncthreads();

  {
    const size_t base = (size_t)(b * NN + i0) * DD;
    v4f s0 = ((const v4f*)red)[tid];
    v4f s1 = ((const v4f*)red)[tid + 256];
    v4f s2 = ((const v4f*)red)[tid + 512];
    v4f s3 = ((const v4f*)red)[tid + 768];
    v4f hv = *(const v4f*)(h + base + (size_t)tid * 4);
    v4f o  = hv + s0 + s1 + s2 + s3;
    *(v4f*)(out + base + (size_t)tid * 4) = o;
  }
}

extern "C" void kernel_launch(void* const* d_in, const int* in_sizes, int n_in,
                              void* d_out, int out_size, void* d_ws, size_t ws_size,
                              hipStream_t stream) {
  const float* h  = (const float*)d_in[0];
  const int* adj  = (const int*)d_in[1];
  const float* W  = (const float*)d_in[2];
  const float* a  = (const float*)d_in[3];

  float* out    = (float*)d_out;
  float* attout = out + (size_t)BB * NN * DD;

  char* ws = (char*)d_ws;
  short* whbT = (short*)ws;                      ws += (size_t)BB * DD * NN * 2;  // 8.39MB
  float* wh1  = (float*)ws;                      ws += (size_t)BB * NN * 4;
  float* wh2  = (float*)ws;                      ws += (size_t)BB * NN * 4;
  float* msg  = (float*)ws;                      ws += (size_t)BB * NN * 4;
  float* rsg  = (float*)ws;                      ws += (size_t)BB * NN * 4;
  unsigned* maskg = (unsigned*)ws;               // 4MB

  gat_k1<<<dim3(NN / 64, BB), 256, 0, stream>>>(h, W, a, whbT, wh1, wh2);
  gat_k0<<<dim3(NN / 4, BB), 256, 0, stream>>>(adj, wh1, wh2, maskg, msg, rsg);
  gat_k2<<<dim3(NN / TR * BB), 256, 0, stream>>>(h, maskg, whbT, wh1, wh2, msg, rsg, out, attout);
}

// Round 7
// 313.115 us; speedup vs baseline: 1.4331x; 1.1535x over previous
//
#include <hip/hip_runtime.h>
#include <cstdint>
#include <cstddef>

typedef float  v4f __attribute__((ext_vector_type(4)));
typedef short  v8s __attribute__((ext_vector_type(8)));
typedef int    v4i __attribute__((ext_vector_type(4)));
typedef unsigned long long u64;

#define BB 8
#define NN 2048
#define DD 128
#define TI 16
#define NEGV (-9e15f)

__device__ __forceinline__ unsigned short f2bf(float x) {
  unsigned u = __float_as_uint(x);
  u = u + 0x7FFFu + ((u >> 16) & 1u);   // round-to-nearest-even
  return (unsigned short)(u >> 16);
}

// packed f32x2 -> bf16x2, RTNE (same rounding as f2bf)
__device__ __forceinline__ unsigned cvt_pk_bf16(float lo, float hi) {
  unsigned r;
  asm("v_cvt_pk_bf16_f32 %0, %1, %2" : "=v"(r) : "v"(lo), "v"(hi));
  return r;
}

// ---------------------------------------------------------------------------
// K1 (MFMA): Wh = h @ W, Wh1 = Wh·a[:128], Wh2 = Wh·a[128:], whbT = bf16(Wh)^T.
// Unchanged (correctness-verified, ~20us).
// ---------------------------------------------------------------------------
__global__ __launch_bounds__(256) void gat_k1(
    const float* __restrict__ h, const float* __restrict__ W, const float* __restrict__ a,
    short* __restrict__ whbT, float* __restrict__ wh1g, float* __restrict__ wh2g)
{
  __shared__ __align__(16) unsigned short wT[DD * 136];
  __shared__ __align__(16) unsigned short staging[DD * 72];

  const int tid  = threadIdx.x;
  const int lane = tid & 63;
  const int wid  = tid >> 6;
  const int m16  = lane & 15;
  const int quad = lane >> 4;
  const int b    = blockIdx.y;
  const int i0   = blockIdx.x * 64;

  {
    const v4f* W4 = (const v4f*)W;
    #pragma unroll
    for (int it = 0; it < 16; it++) {
      int idx = it * 256 + tid;
      int k  = idx >> 5;
      int c4 = (idx & 31) * 4;
      v4f wv = W4[idx];
      #pragma unroll
      for (int q = 0; q < 4; q++)
        wT[(c4 + q) * 136 + k] = f2bf(wv[q]);
    }
  }

  const float* hrow = h + (size_t)(b * NN + i0 + wid * 16 + m16) * DD;
  v8s af[4];
  #pragma unroll
  for (int ks = 0; ks < 4; ks++) {
    v4f x0 = *(const v4f*)(hrow + ks * 32 + quad * 8);
    v4f x1 = *(const v4f*)(hrow + ks * 32 + quad * 8 + 4);
    v8s t;
    t[0] = (short)f2bf(x0.x); t[1] = (short)f2bf(x0.y);
    t[2] = (short)f2bf(x0.z); t[3] = (short)f2bf(x0.w);
    t[4] = (short)f2bf(x1.x); t[5] = (short)f2bf(x1.y);
    t[6] = (short)f2bf(x1.z); t[7] = (short)f2bf(x1.w);
    af[ks] = t;
  }
  __syncthreads();

  v4f acc[8];
  #pragma unroll
  for (int t = 0; t < 8; t++) acc[t] = (v4f){0.f, 0.f, 0.f, 0.f};

  #pragma unroll
  for (int ks = 0; ks < 4; ks++) {
    #pragma unroll
    for (int t = 0; t < 8; t++) {
      v8s bf = *(const v8s*)&wT[(t * 16 + m16) * 136 + ks * 32 + quad * 8];
      acc[t] = __builtin_amdgcn_mfma_f32_16x16x32_bf16(af[ks], bf, acc[t], 0, 0, 0);
    }
  }

  {
    float a1v[8], a2v[8];
    #pragma unroll
    for (int t = 0; t < 8; t++) {
      a1v[t] = a[t * 16 + m16];
      a2v[t] = a[DD + t * 16 + m16];
    }
    #pragma unroll
    for (int r = 0; r < 4; r++) {
      float p1 = 0.f, p2 = 0.f;
      #pragma unroll
      for (int t = 0; t < 8; t++) {
        p1 += acc[t][r] * a1v[t];
        p2 += acc[t][r] * a2v[t];
      }
      #pragma unroll
      for (int off = 8; off > 0; off >>= 1) {
        p1 += __shfl_xor(p1, off);
        p2 += __shfl_xor(p2, off);
      }
      if (m16 == 0) {
        int gi = b * NN + i0 + wid * 16 + quad * 4 + r;
        wh1g[gi] = p1;
        wh2g[gi] = p2;
      }
    }
  }

  #pragma unroll
  for (int t = 0; t < 8; t++)
    #pragma unroll
    for (int r = 0; r < 4; r++)
      staging[(t * 16 + m16) * 72 + wid * 16 + quad * 4 + r] = f2bf(acc[t][r]);
  __syncthreads();

  #pragma unroll
  for (int it = 0; it < 4; it++) {
    int idx = it * 256 + tid;
    int c  = idx >> 3;
    int i8 = idx & 7;
    v8s val = *(const v8s*)&staging[c * 72 + i8 * 8];
    *(v8s*)(whbT + (size_t)b * DD * NN + (size_t)c * NN + i0 + i8 * 8) = val;
  }
}

// ---------------------------------------------------------------------------
// K0' : streaming adj pass + ATT WRITE. One wave per row. The wave holds the
// full row's e[32] in registers; after the m/s reduction it emits the whole
// 2048-float att row as 8 contiguous-1KB v4f stores (fire-and-forget, no
// consumer -> pure streaming writes at high occupancy, fill-kernel regime).
// ---------------------------------------------------------------------------
__global__ __launch_bounds__(256) void gat_k0(
    const int* __restrict__ adj, const float* __restrict__ wh1g,
    const float* __restrict__ wh2g, unsigned* __restrict__ maskg,
    float* __restrict__ msg, float* __restrict__ rsg,
    float* __restrict__ attout)
{
  const int tid  = threadIdx.x;
  const int lane = tid & 63;
  const int wid  = tid >> 6;
  const int b    = blockIdx.y;
  const int i    = blockIdx.x * 4 + wid;
  const size_t row = (size_t)b * NN + i;

  const v4i* arow = (const v4i*)(adj + row * NN);
  const v4f* w2   = (const v4f*)(wh2g + (size_t)b * NN);
  const float wh1v = wh1g[row];

  float e[32];
  float m = -INFINITY;
  unsigned mbits = 0u;
  #pragma unroll
  for (int u = 0; u < 8; u++) {
    v4i av  = __builtin_nontemporal_load(&arow[u * 64 + lane]);
    v4f w2v = w2[u * 64 + lane];
    #pragma unroll
    for (int q = 0; q < 4; q++) {
      bool mk = av[q] > 0;
      float x = wh1v + w2v[q];
      float ev = mk ? (x > 0.f ? x : 0.2f * x) : NEGV;
      e[u * 4 + q] = ev;
      m = fmaxf(m, ev);
      mbits |= (mk ? 1u : 0u) << (u * 4 + q);
    }
  }
  maskg[row * 64 + lane] = mbits;

  #pragma unroll
  for (int off = 32; off > 0; off >>= 1) m = fmaxf(m, __shfl_xor(m, off));
  float s = 0.f;
  #pragma unroll
  for (int k = 0; k < 32; k++) s += __expf(e[k] - m);
  #pragma unroll
  for (int off = 32; off > 0; off >>= 1) s += __shfl_xor(s, off);
  const float rs = 1.f / s;

  if (lane == 0) { msg[row] = m; rsg[row] = rs; }

  // emit the att row: lane covers cols u*256 + lane*4 .. +3 (1KB/line-group)
  float* attrow = attout + row * NN;
  #pragma unroll
  for (int u = 0; u < 8; u++) {
    v4f av;
    #pragma unroll
    for (int q = 0; q < 4; q++)
      av[q] = __expf(e[u * 4 + q] - m) * rs;
    *(v4f*)(attrow + u * 256 + lane * 4) = av;
  }
}

// ---------------------------------------------------------------------------
// K2 v7: EXACTLY the r4 (proven 73us, no-spill) kernel with the att store
// REMOVED. The main loop now contains no HBM stores -> the per-chunk vmcnt
// chain never waits on store retirement. att recomputed only for the bf16
// MFMA A-fragments (cheap VALU on LDS-resident data).
// ---------------------------------------------------------------------------
__global__ __launch_bounds__(256, 4) void gat_k2(
    const float* __restrict__ h, const unsigned* __restrict__ maskg,
    const short* __restrict__ whbT, const float* __restrict__ wh1g,
    const float* __restrict__ wh2g, const float* __restrict__ msg,
    const float* __restrict__ rsg, float* __restrict__ out)
{
  // 32 KB block: [0,8K) wh2s, [8K,16.9K) per-wave atile; whole 32 KB = redbuf in epilogue
  __shared__ __align__(16) float smem[4 * TI * DD];
  __shared__ unsigned masks[TI * 68];
  __shared__ float wh1s[TI], ms_s[TI], rs_s[TI];

  const int tid  = threadIdx.x;
  const int lane = tid & 63;
  const int wid  = tid >> 6;
  const int m16  = lane & 15;
  const int quad = lane >> 4;
  const int bid  = blockIdx.x;
  const int b    = bid & 7;            // XCD swizzle: one batch per XCD
  const int i0   = (bid >> 3) * TI;

  float* wh2s = smem;
  unsigned short* atile = (unsigned short*)(smem + 2048) + wid * (TI * 68);

  {
    const v4f* w2g4 = (const v4f*)(wh2g + (size_t)b * NN);
    ((v4f*)wh2s)[tid]       = w2g4[tid];
    ((v4f*)wh2s)[tid + 256] = w2g4[tid + 256];
  }
  {
    const unsigned* mg = maskg + (size_t)(b * NN + i0) * 64;
    #pragma unroll
    for (int it = 0; it < 4; it++) {
      int idx = it * 256 + tid;
      masks[(idx >> 6) * 68 + (idx & 63)] = mg[idx];
    }
  }
  if (tid < TI) {
    wh1s[tid] = wh1g[b * NN + i0 + tid];
    ms_s[tid] = msg[b * NN + i0 + tid];
    rs_s[tid] = rsg[b * NN + i0 + tid];
  }
  __syncthreads();

  // per-lane row scalars for the 4 rows this lane computes (rows it*4+quad)
  float wh1r[4], mir[4], rsr[4];
  #pragma unroll
  for (int it = 0; it < 4; it++) {
    wh1r[it] = wh1s[it * 4 + quad];
    mir[it]  = ms_s[it * 4 + quad];
    rsr[it]  = rs_s[it * 4 + quad];
  }

  const short* whbT_b = whbT + (size_t)b * DD * NN;

  v4f acc[8];
  #pragma unroll
  for (int t = 0; t < 8; t++) acc[t] = (v4f){0.f, 0.f, 0.f, 0.f};

  for (int c = 0; c < 8; c++) {
    const int j0 = wid * 512 + c * 64;
    const int jb = j0 + quad * 8;

    // 1) B-fragment loads first (L2-resident whbT)
    v8s bfr0[8], bfr1[8];
    #pragma unroll
    for (int t = 0; t < 8; t++)
      bfr0[t] = *(const v8s*)(whbT_b + (size_t)(t * 16 + m16) * NN + jb);
    #pragma unroll
    for (int t = 0; t < 8; t++)
      bfr1[t] = *(const v8s*)(whbT_b + (size_t)(t * 16 + m16) * NN + jb + 32);

    // 2) recompute att (bf16 only) into the wave-private LDS tile
    const int ubit = (j0 >> 8) << 2;
    const int wq   = ((j0 >> 2) & 63) + m16;
    v4f w2v = ((const v4f*)wh2s)[(j0 >> 2) + m16];
    #pragma unroll
    for (int it = 0; it < 4; it++) {
      const int row = it * 4 + quad;
      unsigned mw = masks[row * 68 + wq];
      v4f at;
      #pragma unroll
      for (int q = 0; q < 4; q++) {
        float x = wh1r[it] + w2v[q];
        float ev = ((mw >> (ubit + q)) & 1u) ? (x > 0.f ? x : 0.2f * x) : NEGV;
        at[q] = __expf(ev - mir[it]) * rsr[it];
      }
      unsigned lo = cvt_pk_bf16(at[0], at[1]);
      unsigned hi = cvt_pk_bf16(at[2], at[3]);
      u64 dv = (u64)lo | ((u64)hi << 32);
      *(u64*)&atile[row * 68 + m16 * 4] = dv;
    }

    // 3) A-fragments from LDS in MFMA layout (row = m16, k = ks*32+quad*8)
    union { v8s s; u64 d[2]; } af0, af1;
    af0.d[0] = *(const u64*)&atile[m16 * 68 + quad * 8];
    af0.d[1] = *(const u64*)&atile[m16 * 68 + quad * 8 + 4];
    af1.d[0] = *(const u64*)&atile[m16 * 68 + 32 + quad * 8];
    af1.d[1] = *(const u64*)&atile[m16 * 68 + 32 + quad * 8 + 4];

    // 4) MFMA: 8 d-tiles x K=64
    #pragma unroll
    for (int t = 0; t < 8; t++)
      acc[t] = __builtin_amdgcn_mfma_f32_16x16x32_bf16(af0.s, bfr0[t], acc[t], 0, 0, 0);
    #pragma unroll
    for (int t = 0; t < 8; t++)
      acc[t] = __builtin_amdgcn_mfma_f32_16x16x32_bf16(af1.s, bfr1[t], acc[t], 0, 0, 0);
  }

  // ---- cross-wave reduction of h' partials (smem reused as 32 KB redbuf)
  __syncthreads();
  float* red = smem;
  #pragma unroll
  for (int t = 0; t < 8; t++)
    #pragma unroll
    for (int r = 0; r < 4; r++)
      red[wid * (TI * DD) + (quad * 4 + r) * DD + t * 16 + m16] = acc[t][r];
  __syncthreads();

  {
    const size_t base = (size_t)(b * NN + i0) * DD;
    #pragma unroll
    for (int it = 0; it < 2; it++) {
      int idx = it * 256 + tid;
      v4f s0 = ((const v4f*)red)[idx];
      v4f s1 = ((const v4f*)red)[idx + 512];
      v4f s2 = ((const v4f*)red)[idx + 1024];
      v4f s3 = ((const v4f*)red)[idx + 1536];
      v4f hv = *(const v4f*)(h + base + (size_t)idx * 4);
      v4f o  = hv + s0 + s1 + s2 + s3;
      *(v4f*)(out + base + (size_t)idx * 4) = o;
    }
  }
}

extern "C" void kernel_launch(void* const* d_in, const int* in_sizes, int n_in,
                              void* d_out, int out_size, void* d_ws, size_t ws_size,
                              hipStream_t stream) {
  const float* h  = (const float*)d_in[0];
  const int* adj  = (const int*)d_in[1];
  const float* W  = (const float*)d_in[2];
  const float* a  = (const float*)d_in[3];

  float* out    = (float*)d_out;
  float* attout = out + (size_t)BB * NN * DD;

  char* ws = (char*)d_ws;
  short* whbT = (short*)ws;                      ws += (size_t)BB * DD * NN * 2;  // 8.39MB
  float* wh1  = (float*)ws;                      ws += (size_t)BB * NN * 4;
  float* wh2  = (float*)ws;                      ws += (size_t)BB * NN * 4;
  float* msg  = (float*)ws;                      ws += (size_t)BB * NN * 4;
  float* rsg  = (float*)ws;                      ws += (size_t)BB * NN * 4;
  unsigned* maskg = (unsigned*)ws;               // 4MB

  gat_k1<<<dim3(NN / 64, BB), 256, 0, stream>>>(h, W, a, whbT, wh1, wh2);
  gat_k0<<<dim3(NN / 4, BB), 256, 0, stream>>>(adj, wh1, wh2, maskg, msg, rsg, attout);
  gat_k2<<<dim3(NN / TI * BB), 256, 0, stream>>>(h, maskg, whbT, wh1, wh2, msg, rsg, out);
}

// Round 8
// 281.838 us; speedup vs baseline: 1.5921x; 1.1110x over previous
//
#include <hip/hip_runtime.h>
#include <cstdint>
#include <cstddef>

typedef float  v4f __attribute__((ext_vector_type(4)));
typedef short  v8s __attribute__((ext_vector_type(8)));
typedef int    v4i __attribute__((ext_vector_type(4)));
typedef unsigned long long u64;

#define BB 8
#define NN 2048
#define DD 128
#define TI 16
#define NEGV (-9e15f)

__device__ __forceinline__ unsigned short f2bf(float x) {
  unsigned u = __float_as_uint(x);
  u = u + 0x7FFFu + ((u >> 16) & 1u);   // round-to-nearest-even
  return (unsigned short)(u >> 16);
}

// packed f32x2 -> bf16x2, RTNE (same rounding as f2bf)
__device__ __forceinline__ unsigned cvt_pk_bf16(float lo, float hi) {
  unsigned r;
  asm("v_cvt_pk_bf16_f32 %0, %1, %2" : "=v"(r) : "v"(lo), "v"(hi));
  return r;
}

// ---------------------------------------------------------------------------
// K1 (MFMA): Wh = h @ W, Wh1/Wh2, and Wh^T in TILE-BLOCKED bf16 layout:
// whb4[b][t=8][jc=64][lane=64][8 bf16], tile = 16d x 32j, 1KB, exact MFMA
// B-fragment lane order (lane l: d = t*16+(l&15), j = jc*32+(l>>4)*8..+7).
// K2's B loads then read 1KB fully-contiguous per instruction.
// ---------------------------------------------------------------------------
__global__ __launch_bounds__(256) void gat_k1(
    const float* __restrict__ h, const float* __restrict__ W, const float* __restrict__ a,
    short* __restrict__ whb4, float* __restrict__ wh1g, float* __restrict__ wh2g)
{
  __shared__ __align__(16) unsigned short wT[DD * 136];
  __shared__ __align__(16) unsigned short staging[DD * 72];

  const int tid  = threadIdx.x;
  const int lane = tid & 63;
  const int wid  = tid >> 6;
  const int m16  = lane & 15;
  const int quad = lane >> 4;
  const int b    = blockIdx.y;
  const int i0   = blockIdx.x * 64;

  {
    const v4f* W4 = (const v4f*)W;
    #pragma unroll
    for (int it = 0; it < 16; it++) {
      int idx = it * 256 + tid;
      int k  = idx >> 5;
      int c4 = (idx & 31) * 4;
      v4f wv = W4[idx];
      #pragma unroll
      for (int q = 0; q < 4; q++)
        wT[(c4 + q) * 136 + k] = f2bf(wv[q]);
    }
  }

  const float* hrow = h + (size_t)(b * NN + i0 + wid * 16 + m16) * DD;
  v8s af[4];
  #pragma unroll
  for (int ks = 0; ks < 4; ks++) {
    v4f x0 = *(const v4f*)(hrow + ks * 32 + quad * 8);
    v4f x1 = *(const v4f*)(hrow + ks * 32 + quad * 8 + 4);
    v8s t;
    t[0] = (short)f2bf(x0.x); t[1] = (short)f2bf(x0.y);
    t[2] = (short)f2bf(x0.z); t[3] = (short)f2bf(x0.w);
    t[4] = (short)f2bf(x1.x); t[5] = (short)f2bf(x1.y);
    t[6] = (short)f2bf(x1.z); t[7] = (short)f2bf(x1.w);
    af[ks] = t;
  }
  __syncthreads();

  v4f acc[8];
  #pragma unroll
  for (int t = 0; t < 8; t++) acc[t] = (v4f){0.f, 0.f, 0.f, 0.f};

  #pragma unroll
  for (int ks = 0; ks < 4; ks++) {
    #pragma unroll
    for (int t = 0; t < 8; t++) {
      v8s bf = *(const v8s*)&wT[(t * 16 + m16) * 136 + ks * 32 + quad * 8];
      acc[t] = __builtin_amdgcn_mfma_f32_16x16x32_bf16(af[ks], bf, acc[t], 0, 0, 0);
    }
  }

  {
    float a1v[8], a2v[8];
    #pragma unroll
    for (int t = 0; t < 8; t++) {
      a1v[t] = a[t * 16 + m16];
      a2v[t] = a[DD + t * 16 + m16];
    }
    #pragma unroll
    for (int r = 0; r < 4; r++) {
      float p1 = 0.f, p2 = 0.f;
      #pragma unroll
      for (int t = 0; t < 8; t++) {
        p1 += acc[t][r] * a1v[t];
        p2 += acc[t][r] * a2v[t];
      }
      #pragma unroll
      for (int off = 8; off > 0; off >>= 1) {
        p1 += __shfl_xor(p1, off);
        p2 += __shfl_xor(p2, off);
      }
      if (m16 == 0) {
        int gi = b * NN + i0 + wid * 16 + quad * 4 + r;
        wh1g[gi] = p1;
        wh2g[gi] = p2;
      }
    }
  }

  // staging[d][i_local]: Wh^T for this block's 64 rows
  #pragma unroll
  for (int t = 0; t < 8; t++)
    #pragma unroll
    for (int r = 0; r < 4; r++)
      staging[(t * 16 + m16) * 72 + wid * 16 + quad * 4 + r] = f2bf(acc[t][r]);
  __syncthreads();

  // emit 16 blocked tiles (8 t x 2 jc-local), 1KB each, lane-ordered
  {
    const size_t bbase = (size_t)b * (8 * 64 * 512);   // shorts
    #pragma unroll
    for (int it = 0; it < 4; it++) {
      int idx = wid * 4 + it;          // 0..15
      int t   = idx >> 1;
      int jcl = idx & 1;
      int d   = t * 16 + (lane & 15);
      int jl  = jcl * 32 + (lane >> 4) * 8;
      v8s val = *(const v8s*)&staging[d * 72 + jl];
      size_t off = bbase + ((size_t)t * 64 + (i0 >> 5) + jcl) * 512 + lane * 8;
      *(v8s*)(whb4 + off) = val;       // 64 lanes x 16B = 1KB contiguous
    }
  }
}

// ---------------------------------------------------------------------------
// K0' : streaming adj pass + att write (unchanged from r7).
// ---------------------------------------------------------------------------
__global__ __launch_bounds__(256) void gat_k0(
    const int* __restrict__ adj, const float* __restrict__ wh1g,
    const float* __restrict__ wh2g, unsigned* __restrict__ maskg,
    float* __restrict__ msg, float* __restrict__ rsg,
    float* __restrict__ attout)
{
  const int tid  = threadIdx.x;
  const int lane = tid & 63;
  const int wid  = tid >> 6;
  const int b    = blockIdx.y;
  const int i    = blockIdx.x * 4 + wid;
  const size_t row = (size_t)b * NN + i;

  const v4i* arow = (const v4i*)(adj + row * NN);
  const v4f* w2   = (const v4f*)(wh2g + (size_t)b * NN);
  const float wh1v = wh1g[row];

  float e[32];
  float m = -INFINITY;
  unsigned mbits = 0u;
  #pragma unroll
  for (int u = 0; u < 8; u++) {
    v4i av  = __builtin_nontemporal_load(&arow[u * 64 + lane]);
    v4f w2v = w2[u * 64 + lane];
    #pragma unroll
    for (int q = 0; q < 4; q++) {
      bool mk = av[q] > 0;
      float x = wh1v + w2v[q];
      float ev = mk ? (x > 0.f ? x : 0.2f * x) : NEGV;
      e[u * 4 + q] = ev;
      m = fmaxf(m, ev);
      mbits |= (mk ? 1u : 0u) << (u * 4 + q);
    }
  }
  maskg[row * 64 + lane] = mbits;

  #pragma unroll
  for (int off = 32; off > 0; off >>= 1) m = fmaxf(m, __shfl_xor(m, off));
  float s = 0.f;
  #pragma unroll
  for (int k = 0; k < 32; k++) s += __expf(e[k] - m);
  #pragma unroll
  for (int off = 32; off > 0; off >>= 1) s += __shfl_xor(s, off);
  const float rs = 1.f / s;

  if (lane == 0) { msg[row] = m; rsg[row] = rs; }

  float* attrow = attout + row * NN;
  #pragma unroll
  for (int u = 0; u < 8; u++) {
    v4f av;
    #pragma unroll
    for (int q = 0; q < 4; q++)
      av[q] = __expf(e[u * 4 + q] - m) * rs;
    *(v4f*)(attrow + u * 256 + lane * 4) = av;
  }
}

// ---------------------------------------------------------------------------
// K2 v8: r7 storeless kernel with B-fragment loads from the BLOCKED whb4
// layout -- each load instruction reads 1KB fully contiguous (8 dense lines)
// instead of 16 scattered 4KB-strided half-lines. Attacks the measured
// load-transaction bottleneck (r6: 2x blocks -> 2x time at constant loads).
// ---------------------------------------------------------------------------
__global__ __launch_bounds__(256, 4) void gat_k2(
    const float* __restrict__ h, const unsigned* __restrict__ maskg,
    const short* __restrict__ whb4, const float* __restrict__ wh1g,
    const float* __restrict__ wh2g, const float* __restrict__ msg,
    const float* __restrict__ rsg, float* __restrict__ out)
{
  __shared__ __align__(16) float smem[4 * TI * DD];
  __shared__ unsigned masks[TI * 68];
  __shared__ float wh1s[TI], ms_s[TI], rs_s[TI];

  const int tid  = threadIdx.x;
  const int lane = tid & 63;
  const int wid  = tid >> 6;
  const int m16  = lane & 15;
  const int quad = lane >> 4;
  const int bid  = blockIdx.x;
  const int b    = bid & 7;            // XCD swizzle: one batch per XCD
  const int i0   = (bid >> 3) * TI;

  float* wh2s = smem;
  unsigned short* atile = (unsigned short*)(smem + 2048) + wid * (TI * 68);

  {
    const v4f* w2g4 = (const v4f*)(wh2g + (size_t)b * NN);
    ((v4f*)wh2s)[tid]       = w2g4[tid];
    ((v4f*)wh2s)[tid + 256] = w2g4[tid + 256];
  }
  {
    const unsigned* mg = maskg + (size_t)(b * NN + i0) * 64;
    #pragma unroll
    for (int it = 0; it < 4; it++) {
      int idx = it * 256 + tid;
      masks[(idx >> 6) * 68 + (idx & 63)] = mg[idx];
    }
  }
  if (tid < TI) {
    wh1s[tid] = wh1g[b * NN + i0 + tid];
    ms_s[tid] = msg[b * NN + i0 + tid];
    rs_s[tid] = rsg[b * NN + i0 + tid];
  }
  __syncthreads();

  float wh1r[4], mir[4], rsr[4];
  #pragma unroll
  for (int it = 0; it < 4; it++) {
    wh1r[it] = wh1s[it * 4 + quad];
    mir[it]  = ms_s[it * 4 + quad];
    rsr[it]  = rs_s[it * 4 + quad];
  }

  const short* whb4_b = whb4 + (size_t)b * (8 * 64 * 512);

  v4f acc[8];
  #pragma unroll
  for (int t = 0; t < 8; t++) acc[t] = (v4f){0.f, 0.f, 0.f, 0.f};

  for (int c = 0; c < 8; c++) {
    const int j0 = wid * 512 + c * 64;
    const int jc = j0 >> 5;              // even tile index

    // 1) B-fragment loads: 1KB contiguous per instruction
    v8s bfr0[8], bfr1[8];
    #pragma unroll
    for (int t = 0; t < 8; t++)
      bfr0[t] = *(const v8s*)(whb4_b + ((size_t)t * 64 + jc) * 512 + lane * 8);
    #pragma unroll
    for (int t = 0; t < 8; t++)
      bfr1[t] = *(const v8s*)(whb4_b + ((size_t)t * 64 + jc + 1) * 512 + lane * 8);

    // 2) recompute att (bf16 only) into the wave-private LDS tile
    const int ubit = (j0 >> 8) << 2;
    const int wq   = ((j0 >> 2) & 63) + m16;
    v4f w2v = ((const v4f*)wh2s)[(j0 >> 2) + m16];
    #pragma unroll
    for (int it = 0; it < 4; it++) {
      const int row = it * 4 + quad;
      unsigned mw = masks[row * 68 + wq];
      v4f at;
      #pragma unroll
      for (int q = 0; q < 4; q++) {
        float x = wh1r[it] + w2v[q];
        float ev = ((mw >> (ubit + q)) & 1u) ? (x > 0.f ? x : 0.2f * x) : NEGV;
        at[q] = __expf(ev - mir[it]) * rsr[it];
      }
      unsigned lo = cvt_pk_bf16(at[0], at[1]);
      unsigned hi = cvt_pk_bf16(at[2], at[3]);
      u64 dv = (u64)lo | ((u64)hi << 32);
      *(u64*)&atile[row * 68 + m16 * 4] = dv;
    }

    // 3) A-fragments from LDS in MFMA layout
    union { v8s s; u64 d[2]; } af0, af1;
    af0.d[0] = *(const u64*)&atile[m16 * 68 + quad * 8];
    af0.d[1] = *(const u64*)&atile[m16 * 68 + quad * 8 + 4];
    af1.d[0] = *(const u64*)&atile[m16 * 68 + 32 + quad * 8];
    af1.d[1] = *(const u64*)&atile[m16 * 68 + 32 + quad * 8 + 4];

    // 4) MFMA: 8 d-tiles x K=64
    #pragma unroll
    for (int t = 0; t < 8; t++)
      acc[t] = __builtin_amdgcn_mfma_f32_16x16x32_bf16(af0.s, bfr0[t], acc[t], 0, 0, 0);
    #pragma unroll
    for (int t = 0; t < 8; t++)
      acc[t] = __builtin_amdgcn_mfma_f32_16x16x32_bf16(af1.s, bfr1[t], acc[t], 0, 0, 0);
  }

  // ---- cross-wave reduction of h' partials
  __syncthreads();
  float* red = smem;
  #pragma unroll
  for (int t = 0; t < 8; t++)
    #pragma unroll
    for (int r = 0; r < 4; r++)
      red[wid * (TI * DD) + (quad * 4 + r) * DD + t * 16 + m16] = acc[t][r];
  __syncthreads();

  {
    const size_t base = (size_t)(b * NN + i0) * DD;
    #pragma unroll
    for (int it = 0; it < 2; it++) {
      int idx = it * 256 + tid;
      v4f s0 = ((const v4f*)red)[idx];
      v4f s1 = ((const v4f*)red)[idx + 512];
      v4f s2 = ((const v4f*)red)[idx + 1024];
      v4f s3 = ((const v4f*)red)[idx + 1536];
      v4f hv = *(const v4f*)(h + base + (size_t)idx * 4);
      v4f o  = hv + s0 + s1 + s2 + s3;
      *(v4f*)(out + base + (size_t)idx * 4) = o;
    }
  }
}

extern "C" void kernel_launch(void* const* d_in, const int* in_sizes, int n_in,
                              void* d_out, int out_size, void* d_ws, size_t ws_size,
                              hipStream_t stream) {
  const float* h  = (const float*)d_in[0];
  const int* adj  = (const int*)d_in[1];
  const float* W  = (const float*)d_in[2];
  const float* a  = (const float*)d_in[3];

  float* out    = (float*)d_out;
  float* attout = out + (size_t)BB * NN * DD;

  char* ws = (char*)d_ws;
  short* whb4 = (short*)ws;                      ws += (size_t)BB * 8 * 64 * 512 * 2;  // 4MB
  float* wh1  = (float*)ws;                      ws += (size_t)BB * NN * 4;
  float* wh2  = (float*)ws;                      ws += (size_t)BB * NN * 4;
  float* msg  = (float*)ws;                      ws += (size_t)BB * NN * 4;
  float* rsg  = (float*)ws;                      ws += (size_t)BB * NN * 4;
  unsigned* maskg = (unsigned*)ws;               // 4MB

  gat_k1<<<dim3(NN / 64, BB), 256, 0, stream>>>(h, W, a, whb4, wh1, wh2);
  gat_k0<<<dim3(NN / 4, BB), 256, 0, stream>>>(adj, wh1, wh2, maskg, msg, rsg, attout);
  gat_k2<<<dim3(NN / TI * BB), 256, 0, stream>>>(h, maskg, whb4, wh1, wh2, msg, rsg, out);
}

// Round 10
// 280.836 us; speedup vs baseline: 1.5978x; 1.0036x over previous
//
#include <hip/hip_runtime.h>
#include <cstdint>
#include <cstddef>

typedef float  v4f __attribute__((ext_vector_type(4)));
typedef short  v8s __attribute__((ext_vector_type(8)));
typedef int    v4i __attribute__((ext_vector_type(4)));
typedef unsigned long long u64;

#define BB 8
#define NN 2048
#define DD 128
#define TI 16
#define NEGV (-9e15f)

__device__ __forceinline__ unsigned short f2bf(float x) {
  unsigned u = __float_as_uint(x);
  u = u + 0x7FFFu + ((u >> 16) & 1u);   // round-to-nearest-even
  return (unsigned short)(u >> 16);
}

// packed f32x2 -> bf16x2, RTNE (same rounding as f2bf)
__device__ __forceinline__ unsigned cvt_pk_bf16(float lo, float hi) {
  unsigned r;
  asm("v_cvt_pk_bf16_f32 %0, %1, %2" : "=v"(r) : "v"(lo), "v"(hi));
  return r;
}

union afrag { v8s s; unsigned u[4]; };

// ---------------------------------------------------------------------------
// K1: Wh = h @ W, Wh1/Wh2, Wh^T in TILE-BLOCKED bf16 layout (unchanged, r8).
// whb4[b][t=8][jc=64][lane=64][8 bf16]: tile = 16d x 32j, 1KB, MFMA lane order.
// ---------------------------------------------------------------------------
__global__ __launch_bounds__(256) void gat_k1(
    const float* __restrict__ h, const float* __restrict__ W, const float* __restrict__ a,
    short* __restrict__ whb4, float* __restrict__ wh1g, float* __restrict__ wh2g)
{
  __shared__ __align__(16) unsigned short wT[DD * 136];
  __shared__ __align__(16) unsigned short staging[DD * 72];

  const int tid  = threadIdx.x;
  const int lane = tid & 63;
  const int wid  = tid >> 6;
  const int m16  = lane & 15;
  const int quad = lane >> 4;
  const int b    = blockIdx.y;
  const int i0   = blockIdx.x * 64;

  {
    const v4f* W4 = (const v4f*)W;
    #pragma unroll
    for (int it = 0; it < 16; it++) {
      int idx = it * 256 + tid;
      int k  = idx >> 5;
      int c4 = (idx & 31) * 4;
      v4f wv = W4[idx];
      #pragma unroll
      for (int q = 0; q < 4; q++)
        wT[(c4 + q) * 136 + k] = f2bf(wv[q]);
    }
  }

  const float* hrow = h + (size_t)(b * NN + i0 + wid * 16 + m16) * DD;
  v8s af[4];
  #pragma unroll
  for (int ks = 0; ks < 4; ks++) {
    v4f x0 = *(const v4f*)(hrow + ks * 32 + quad * 8);
    v4f x1 = *(const v4f*)(hrow + ks * 32 + quad * 8 + 4);
    v8s t;
    t[0] = (short)f2bf(x0.x); t[1] = (short)f2bf(x0.y);
    t[2] = (short)f2bf(x0.z); t[3] = (short)f2bf(x0.w);
    t[4] = (short)f2bf(x1.x); t[5] = (short)f2bf(x1.y);
    t[6] = (short)f2bf(x1.z); t[7] = (short)f2bf(x1.w);
    af[ks] = t;
  }
  __syncthreads();

  v4f acc[8];
  #pragma unroll
  for (int t = 0; t < 8; t++) acc[t] = (v4f){0.f, 0.f, 0.f, 0.f};

  #pragma unroll
  for (int ks = 0; ks < 4; ks++) {
    #pragma unroll
    for (int t = 0; t < 8; t++) {
      v8s bf = *(const v8s*)&wT[(t * 16 + m16) * 136 + ks * 32 + quad * 8];
      acc[t] = __builtin_amdgcn_mfma_f32_16x16x32_bf16(af[ks], bf, acc[t], 0, 0, 0);
    }
  }

  {
    float a1v[8], a2v[8];
    #pragma unroll
    for (int t = 0; t < 8; t++) {
      a1v[t] = a[t * 16 + m16];
      a2v[t] = a[DD + t * 16 + m16];
    }
    #pragma unroll
    for (int r = 0; r < 4; r++) {
      float p1 = 0.f, p2 = 0.f;
      #pragma unroll
      for (int t = 0; t < 8; t++) {
        p1 += acc[t][r] * a1v[t];
        p2 += acc[t][r] * a2v[t];
      }
      #pragma unroll
      for (int off = 8; off > 0; off >>= 1) {
        p1 += __shfl_xor(p1, off);
        p2 += __shfl_xor(p2, off);
      }
      if (m16 == 0) {
        int gi = b * NN + i0 + wid * 16 + quad * 4 + r;
        wh1g[gi] = p1;
        wh2g[gi] = p2;
      }
    }
  }

  #pragma unroll
  for (int t = 0; t < 8; t++)
    #pragma unroll
    for (int r = 0; r < 4; r++)
      staging[(t * 16 + m16) * 72 + wid * 16 + quad * 4 + r] = f2bf(acc[t][r]);
  __syncthreads();

  {
    const size_t bbase = (size_t)b * (8 * 64 * 512);   // shorts
    #pragma unroll
    for (int it = 0; it < 4; it++) {
      int idx = wid * 4 + it;          // 0..15
      int t   = idx >> 1;
      int jcl = idx & 1;
      int d   = t * 16 + (lane & 15);
      int jl  = jcl * 32 + (lane >> 4) * 8;
      v8s val = *(const v8s*)&staging[d * 72 + jl];
      size_t off = bbase + ((size_t)t * 64 + (i0 >> 5) + jcl) * 512 + lane * 8;
      *(v8s*)(whb4 + off) = val;       // 64 lanes x 16B = 1KB contiguous
    }
  }
}

// ---------------------------------------------------------------------------
// K0' : streaming adj pass + att write (unchanged from r7, ~45us = roofline).
// ---------------------------------------------------------------------------
__global__ __launch_bounds__(256) void gat_k0(
    const int* __restrict__ adj, const float* __restrict__ wh1g,
    const float* __restrict__ wh2g, unsigned* __restrict__ maskg,
    float* __restrict__ msg, float* __restrict__ rsg,
    float* __restrict__ attout)
{
  const int tid  = threadIdx.x;
  const int lane = tid & 63;
  const int wid  = tid >> 6;
  const int b    = blockIdx.y;
  const int i    = blockIdx.x * 4 + wid;
  const size_t row = (size_t)b * NN + i;

  const v4i* arow = (const v4i*)(adj + row * NN);
  const v4f* w2   = (const v4f*)(wh2g + (size_t)b * NN);
  const float wh1v = wh1g[row];

  float e[32];
  float m = -INFINITY;
  unsigned mbits = 0u;
  #pragma unroll
  for (int u = 0; u < 8; u++) {
    v4i av  = __builtin_nontemporal_load(&arow[u * 64 + lane]);
    v4f w2v = w2[u * 64 + lane];
    #pragma unroll
    for (int q = 0; q < 4; q++) {
      bool mk = av[q] > 0;
      float x = wh1v + w2v[q];
      float ev = mk ? (x > 0.f ? x : 0.2f * x) : NEGV;
      e[u * 4 + q] = ev;
      m = fmaxf(m, ev);
      mbits |= (mk ? 1u : 0u) << (u * 4 + q);
    }
  }
  maskg[row * 64 + lane] = mbits;

  #pragma unroll
  for (int off = 32; off > 0; off >>= 1) m = fmaxf(m, __shfl_xor(m, off));
  float s = 0.f;
  #pragma unroll
  for (int k = 0; k < 32; k++) s += __expf(e[k] - m);
  #pragma unroll
  for (int off = 32; off > 0; off >>= 1) s += __shfl_xor(s, off);
  const float rs = 1.f / s;

  if (lane == 0) { msg[row] = m; rsg[row] = rs; }

  float* attrow = attout + row * NN;
  #pragma unroll
  for (int u = 0; u < 8; u++) {
    v4f av;
    #pragma unroll
    for (int q = 0; q < 4; q++)
      av[q] = __expf(e[u * 4 + q] - m) * rs;
    *(v4f*)(attrow + u * 256 + lane * 4) = av;
  }
}

// ---------------------------------------------------------------------------
// K2 v9: att computed DIRECTLY in MFMA A-fragment layout (lane -> row m16,
// k-cols quad*8..+7) -- zero LDS in the main loop. Removes the per-chunk
// ds_write->lgkmcnt(0)->ds_read serialization and frees registers so the 16
// dense B loads can stay in flight (r8's VGPR=64 showed they were serialized).
// ---------------------------------------------------------------------------
__global__ __launch_bounds__(256, 4) void gat_k2(
    const float* __restrict__ h, const unsigned* __restrict__ maskg,
    const short* __restrict__ whb4, const float* __restrict__ wh1g,
    const float* __restrict__ wh2g, const float* __restrict__ msg,
    const float* __restrict__ rsg, float* __restrict__ out)
{
  __shared__ __align__(16) float smem[4 * TI * DD];   // wh2s (8KB) / epilogue red (32KB)
  __shared__ unsigned masks[TI * 68];
  __shared__ float wh1s[TI], ms_s[TI], rs_s[TI];

  const int tid  = threadIdx.x;
  const int lane = tid & 63;
  const int wid  = tid >> 6;
  const int m16  = lane & 15;
  const int quad = lane >> 4;
  const int bid  = blockIdx.x;
  const int b    = bid & 7;            // XCD swizzle: one batch per XCD
  const int i0   = (bid >> 3) * TI;

  float* wh2s = smem;

  {
    const v4f* w2g4 = (const v4f*)(wh2g + (size_t)b * NN);
    ((v4f*)wh2s)[tid]       = w2g4[tid];
    ((v4f*)wh2s)[tid + 256] = w2g4[tid + 256];
  }
  {
    const unsigned* mg = maskg + (size_t)(b * NN + i0) * 64;
    #pragma unroll
    for (int it = 0; it < 4; it++) {
      int idx = it * 256 + tid;
      masks[(idx >> 6) * 68 + (idx & 63)] = mg[idx];
    }
  }
  if (tid < TI) {
    wh1s[tid] = wh1g[b * NN + i0 + tid];
    ms_s[tid] = msg[b * NN + i0 + tid];
    rs_s[tid] = rsg[b * NN + i0 + tid];
  }
  __syncthreads();

  // per-lane row scalars: this lane's A-fragment row is m16
  const float wh1v = wh1s[m16];
  const float mi   = ms_s[m16];
  const float rsi  = rs_s[m16];

  const short* whb4_b = whb4 + (size_t)b * (8 * 64 * 512);

  v4f acc[8];
  #pragma unroll
  for (int t = 0; t < 8; t++) acc[t] = (v4f){0.f, 0.f, 0.f, 0.f};

  for (int c = 0; c < 8; c++) {
    const int j0 = wid * 512 + c * 64;
    const int jc = j0 >> 5;              // even tile index

    // 1) B-fragment loads: 1KB contiguous per instruction
    v8s bfr0[8], bfr1[8];
    #pragma unroll
    for (int t = 0; t < 8; t++)
      bfr0[t] = *(const v8s*)(whb4_b + ((size_t)t * 64 + jc) * 512 + lane * 8);
    #pragma unroll
    for (int t = 0; t < 8; t++)
      bfr1[t] = *(const v8s*)(whb4_b + ((size_t)t * 64 + jc + 1) * 512 + lane * 8);

    // 2) att directly in A-fragment layout: row m16, k = ks*32 + quad*8 .. +7
    const int ubit = (j0 >> 8) << 2;     // bit = (j>>8)*4 + (j&3)
    afrag af0, af1;
    #pragma unroll
    for (int ks = 0; ks < 2; ks++) {
      const int jb = j0 + ks * 32 + quad * 8;
      v4f w2a = ((const v4f*)wh2s)[jb >> 2];
      v4f w2b = ((const v4f*)wh2s)[(jb >> 2) + 1];
      const int w0 = (jb >> 2) & 63;
      unsigned mwa = masks[m16 * 68 + w0];
      unsigned mwb = masks[m16 * 68 + w0 + 1];
      v4f at0, at1;
      #pragma unroll
      for (int q = 0; q < 4; q++) {
        float x = wh1v + w2a[q];
        float ev = ((mwa >> (ubit + q)) & 1u) ? (x > 0.f ? x : 0.2f * x) : NEGV;
        at0[q] = __expf(ev - mi) * rsi;
      }
      #pragma unroll
      for (int q = 0; q < 4; q++) {
        float x = wh1v + w2b[q];
        float ev = ((mwb >> (ubit + q)) & 1u) ? (x > 0.f ? x : 0.2f * x) : NEGV;
        at1[q] = __expf(ev - mi) * rsi;
      }
      afrag* afp = ks ? &af1 : &af0;
      afp->u[0] = cvt_pk_bf16(at0[0], at0[1]);
      afp->u[1] = cvt_pk_bf16(at0[2], at0[3]);
      afp->u[2] = cvt_pk_bf16(at1[0], at1[1]);
      afp->u[3] = cvt_pk_bf16(at1[2], at1[3]);
    }

    // 3) MFMA: 8 d-tiles x K=64
    #pragma unroll
    for (int t = 0; t < 8; t++)
      acc[t] = __builtin_amdgcn_mfma_f32_16x16x32_bf16(af0.s, bfr0[t], acc[t], 0, 0, 0);
    #pragma unroll
    for (int t = 0; t < 8; t++)
      acc[t] = __builtin_amdgcn_mfma_f32_16x16x32_bf16(af1.s, bfr1[t], acc[t], 0, 0, 0);
  }

  // ---- cross-wave reduction of h' partials (smem reused as 32 KB redbuf)
  __syncthreads();
  float* red = smem;
  #pragma unroll
  for (int t = 0; t < 8; t++)
    #pragma unroll
    for (int r = 0; r < 4; r++)
      red[wid * (TI * DD) + (quad * 4 + r) * DD + t * 16 + m16] = acc[t][r];
  __syncthreads();

  {
    const size_t base = (size_t)(b * NN + i0) * DD;
    #pragma unroll
    for (int it = 0; it < 2; it++) {
      int idx = it * 256 + tid;
      v4f s0 = ((const v4f*)red)[idx];
      v4f s1 = ((const v4f*)red)[idx + 512];
      v4f s2 = ((const v4f*)red)[idx + 1024];
      v4f s3 = ((const v4f*)red)[idx + 1536];
      v4f hv = *(const v4f*)(h + base + (size_t)idx * 4);
      v4f o  = hv + s0 + s1 + s2 + s3;
      *(v4f*)(out + base + (size_t)idx * 4) = o;
    }
  }
}

extern "C" void kernel_launch(void* const* d_in, const int* in_sizes, int n_in,
                              void* d_out, int out_size, void* d_ws, size_t ws_size,
                              hipStream_t stream) {
  const float* h  = (const float*)d_in[0];
  const int* adj  = (const int*)d_in[1];
  const float* W  = (const float*)d_in[2];
  const float* a  = (const float*)d_in[3];

  float* out    = (float*)d_out;
  float* attout = out + (size_t)BB * NN * DD;

  char* ws = (char*)d_ws;
  short* whb4 = (short*)ws;                      ws += (size_t)BB * 8 * 64 * 512 * 2;  // 4MB
  float* wh1  = (float*)ws;                      ws += (size_t)BB * NN * 4;
  float* wh2  = (float*)ws;                      ws += (size_t)BB * NN * 4;
  float* msg  = (float*)ws;                      ws += (size_t)BB * NN * 4;
  float* rsg  = (float*)ws;                      ws += (size_t)BB * NN * 4;
  unsigned* maskg = (unsigned*)ws;               // 4MB

  gat_k1<<<dim3(NN / 64, BB), 256, 0, stream>>>(h, W, a, whb4, wh1, wh2);
  gat_k0<<<dim3(NN / 4, BB), 256, 0, stream>>>(adj, wh1, wh2, maskg, msg, rsg, attout);
  gat_k2<<<dim3(NN / TI * BB), 256, 0, stream>>>(h, maskg, whb4, wh1, wh2, msg, rsg, out);
}